// Round 3
// baseline (141.478 us; speedup 1.0000x reference)
//
#include <hip/hip_runtime.h>
#include <hip/hip_fp16.h>
#include <math.h>

#define NPOS 13824   // 24*24*24
#define CDIM 64
#define BTCH 2
#define LOG2E 1.4426950408889634f
#define QSCALE (0.125f * LOG2E)

typedef _Float16 f16;
typedef f16 f16x8 __attribute__((ext_vector_type(8)));
typedef f16 f16x4 __attribute__((ext_vector_type(4)));
typedef float f32x4 __attribute__((ext_vector_type(4)));

__device__ __forceinline__ unsigned int f2bf1(float f) {   // RNE float->bf16
  unsigned int u = __float_as_uint(f);
  return (u + 0x7FFFu + ((u >> 16) & 1u)) >> 16;
}

__device__ __forceinline__ unsigned int pkh2(float a, float b) {  // {lo=a, hi=b} f16 pair
  __half2 h = __floats2half2_rn(a, b);
  return *reinterpret_cast<unsigned int*>(&h);
}

// ---------------------------------------------------------------------------
// Kernel 1 (MFMA): 256x64 f16 A (rows 0-63 Wq*QSCALE, 64-127 Wg[:, :64],
// 128-255 {K_c,V_c} interleaved) x 64-pos x-tile. Outputs all (N,C):
//   Qh  f16  pre-scaled Q
//   KVp u32  bf16 K|V packed (bias included)
//   G1h f16  gate partial Wg1*x + bg
// Zeroes pool + counter.
// ---------------------------------------------------------------------------
__global__ __launch_bounds__(256) void qkvg_kernel(
    const float* __restrict__ x,
    const float* __restrict__ Wq, const float* __restrict__ bq,
    const float* __restrict__ Wk, const float* __restrict__ bk,
    const float* __restrict__ Wv, const float* __restrict__ bv,
    const float* __restrict__ Wg, const float* __restrict__ bg,
    f16* __restrict__ Qh, unsigned int* __restrict__ KVp,
    f16* __restrict__ G1h, float* __restrict__ pool)
{
  __shared__ __align__(16) unsigned short ws[256*64];  // f16 weights, 32 KB
  __shared__ __align__(16) unsigned short xs[64*64];   // f16 x [pos][ch], 8 KB
  const int t  = threadIdx.x;
  const int bi = blockIdx.x;
  const int b  = bi / 216;
  const int n0 = (bi - b*216) * 64;
  if (bi == 0 && t < 132) pool[t] = 0.0f;   // pool[128] doubles as counter

  // ---- stage weights: row-XOR swizzle ----
  #pragma unroll
  for (int k = 0; k < 4; ++k) {
    const int u  = t + k*256;            // 0..1023
    const int r  = u >> 4;               // source row 0..63
    const int i0 = (u & 15) * 4;         // in-ch 0..60 step 4
    const float4 q4 = *(const float4*)&Wq[r*64  + i0];
    const float4 g4 = *(const float4*)&Wg[r*128 + i0];
    const float4 k4 = *(const float4*)&Wk[r*64  + i0];
    const float4 v4 = *(const float4*)&Wv[r*64  + i0];
    {
      const int rr = r;
      const int idx = (rr*64 + i0) ^ ((rr & 7) << 3);
      *(uint2*)&ws[idx] = make_uint2(pkh2(q4.x*QSCALE, q4.y*QSCALE),
                                     pkh2(q4.z*QSCALE, q4.w*QSCALE));
    }
    {
      const int rr = 64 + r;
      const int idx = (rr*64 + i0) ^ ((rr & 7) << 3);
      *(uint2*)&ws[idx] = make_uint2(pkh2(g4.x, g4.y), pkh2(g4.z, g4.w));
    }
    {
      const int rr = 128 + 2*r;          // K channel r
      const int idx = (rr*64 + i0) ^ ((rr & 7) << 3);
      *(uint2*)&ws[idx] = make_uint2(pkh2(k4.x, k4.y), pkh2(k4.z, k4.w));
    }
    {
      const int rr = 129 + 2*r;          // V channel r
      const int idx = (rr*64 + i0) ^ ((rr & 7) << 3);
      *(uint2*)&ws[idx] = make_uint2(pkh2(v4.x, v4.y), pkh2(v4.z, v4.w));
    }
  }
  // ---- stage x tile as f16 [pos][ch], coalesced along pos ----
  {
    const int p = t & 63;
    const size_t xb = (size_t)(b*64)*NPOS + n0 + p;
    #pragma unroll
    for (int k = 0; k < 8; ++k) {
      const int ch0 = (t >> 6) * 2 + k * 8;       // even channels
      const float a0 = x[xb + (size_t)ch0*NPOS];
      const float a1 = x[xb + (size_t)(ch0+1)*NPOS];
      const int idx = (p*64 + ch0) ^ ((p & 7) << 3);
      *(unsigned int*)&xs[idx] = pkh2(a0, a1);
    }
  }
  __syncthreads();

  const int l   = t & 63;
  const int w   = t >> 6;
  const int lr  = l & 15;              // fragment row (A) / col (B,C)
  const int lkb = (l >> 4) * 8;        // k-slot base (consistent for A and B)
  const int swz = (lr & 7) << 3;

  f16x8 Bf[4][2];
  #pragma unroll
  for (int nf = 0; nf < 4; ++nf)
    #pragma unroll
    for (int kk = 0; kk < 2; ++kk) {
      const int prow = nf*16 + lr;
      Bf[nf][kk] = *(const f16x8*)&xs[(prow*64 + kk*32 + lkb) ^ swz];
    }
  f16x8 Af[4][2];
  #pragma unroll
  for (int f = 0; f < 4; ++f)
    #pragma unroll
    for (int kk = 0; kk < 2; ++kk) {
      const int row = (w*4 + f)*16 + lr;
      Af[f][kk] = *(const f16x8*)&ws[(row*64 + kk*32 + lkb) ^ swz];
    }
  f32x4 acc[4][4];
  #pragma unroll
  for (int f = 0; f < 4; ++f)
    #pragma unroll
    for (int nf = 0; nf < 4; ++nf) {
      f32x4 z = {0.f, 0.f, 0.f, 0.f};
      z = __builtin_amdgcn_mfma_f32_16x16x32_f16(Af[f][0], Bf[nf][0], z, 0, 0, 0);
      acc[f][nf] = __builtin_amdgcn_mfma_f32_16x16x32_f16(Af[f][1], Bf[nf][1], z, 0, 0, 0);
    }

  // ---- epilogue: C/D mapping col=lane&15 (pos), row=(lane>>4)*4+reg (ch) ----
  const int rsub  = (l >> 4) * 4;
  const int pbase = b*NPOS + n0;
  if (w == 0) {                    // ---- Q: +bq*QSCALE, pack f16 ----
    #pragma unroll
    for (int f = 0; f < 4; ++f) {
      const int ch0 = f*16 + rsub;
      const float4 bq4 = *(const float4*)&bq[ch0];
      #pragma unroll
      for (int nf = 0; nf < 4; ++nf) {
        const int p = pbase + nf*16 + lr;
        uint2 o;
        o.x = pkh2(fmaf(bq4.x, QSCALE, acc[f][nf].x),
                   fmaf(bq4.y, QSCALE, acc[f][nf].y));
        o.y = pkh2(fmaf(bq4.z, QSCALE, acc[f][nf].z),
                   fmaf(bq4.w, QSCALE, acc[f][nf].w));
        *(uint2*)&Qh[(size_t)p*64 + ch0] = o;
      }
    }
  } else if (w == 1) {             // ---- G1 = Wg1*x + bg, pack f16 ----
    #pragma unroll
    for (int f = 0; f < 4; ++f) {
      const int ch0 = f*16 + rsub;
      const float4 bg4 = *(const float4*)&bg[ch0];
      #pragma unroll
      for (int nf = 0; nf < 4; ++nf) {
        const int p = pbase + nf*16 + lr;
        uint2 o;
        o.x = pkh2(acc[f][nf].x + bg4.x, acc[f][nf].y + bg4.y);
        o.y = pkh2(acc[f][nf].z + bg4.z, acc[f][nf].w + bg4.w);
        *(uint2*)&G1h[(size_t)p*64 + ch0] = o;
      }
    }
  } else {                         // ---- K|V: bf16 pack, uint2 stores ----
    #pragma unroll
    for (int f = 0; f < 4; ++f) {
      const int c0 = (w - 2)*32 + f*8 + (l >> 4)*2;   // even channel base
      const float2 bk2 = *(const float2*)&bk[c0];
      const float2 bv2 = *(const float2*)&bv[c0];
      #pragma unroll
      for (int nf = 0; nf < 4; ++nf) {
        const int p = pbase + nf*16 + lr;
        uint2 kv;
        kv.x = (f2bf1(acc[f][nf].x + bk2.x) << 16) | f2bf1(acc[f][nf].y + bv2.x);
        kv.y = (f2bf1(acc[f][nf].z + bk2.y) << 16) | f2bf1(acc[f][nf].w + bv2.y);
        *(uint2*)&KVp[(size_t)p*64 + c0] = kv;
      }
    }
  }
}

// ---------------------------------------------------------------------------
// Kernel 2: PURE attention (gate/blend/pool moved to kernel 3). XCD-swizzled
// 3x3x3 tiles; 5x5x5 bf16 K|V halo in channel-major LDS (stride 127,
// bank-bijective, ds_read2-fusable). No max pass; two positions per wave
// iteration. Reads Qh f16, writes ATTh f16 (both (N,C), coalesced).
// ---------------------------------------------------------------------------
__global__ __launch_bounds__(256, 4) void attn_kernel(
    const f16* __restrict__ Qh,
    const unsigned int* __restrict__ KVp,
    f16* __restrict__ ATTh,
    const float* __restrict__ bk, const float* __restrict__ bv,
    const float* __restrict__ memk, const float* __restrict__ memv)
{
  __shared__ __align__(16) unsigned int kvbuf2[64*127 + 64]; // ch-major, ~32 KB
  const int t = threadIdx.x;
  const int c = t & 63;
  const int w = t >> 6;

  float mk[5], mv[5];
  #pragma unroll
  for (int m = 0; m < 5; ++m) { mk[m] = memk[c*5 + m]; mv[m] = memv[c*5 + m]; }

  // XCD-aware swizzle: bi&7 = XCD; contiguous 128-tile slab per XCD
  const int bi = (int)(blockIdx.x & 7) * 128 + (int)(blockIdx.x >> 3);
  const int b  = bi >> 9;                 // 512 tiles (8x8x8) per batch
  const int tb = bi & 511;
  const int h0 = (tb >> 6) * 3;
  const int d0 = ((tb >> 3) & 7) * 3;
  const int w0 = (tb & 7) * 3;
  const int bN = b * NPOS;

  // stage 5x5x5 packed K/V halo into channel-major LDS (OOB -> bias)
  for (int u = t; u < 125*16; u += 256) {
    int pos = u >> 4, q4 = u & 15;
    int ph = pos / 25, pr = pos - ph*25;
    int pd = pr / 5,  pw = pr - pd*5;
    int hh = h0 - 1 + ph, dd = d0 - 1 + pd, ww = w0 - 1 + pw;
    bool inb = ((unsigned)hh < 24u) && ((unsigned)dd < 24u) && ((unsigned)ww < 24u);
    uint4 kv;
    if (inb) {
      kv = *(const uint4*)(KVp + ((size_t)(bN + hh*576 + dd*24 + ww))*64 + q4*4);
    } else {
      const float4 kf = ((const float4*)bk)[q4];
      const float4 vf = ((const float4*)bv)[q4];
      kv.x = (f2bf1(kf.x) << 16) | f2bf1(vf.x);
      kv.y = (f2bf1(kf.y) << 16) | f2bf1(vf.y);
      kv.z = (f2bf1(kf.z) << 16) | f2bf1(vf.z);
      kv.w = (f2bf1(kf.w) << 16) | f2bf1(vf.w);
    }
    kvbuf2[(4*q4 + 0)*127 + pos] = kv.x;   // 2-way bank aliasing only (free)
    kvbuf2[(4*q4 + 1)*127 + pos] = kv.y;
    kvbuf2[(4*q4 + 2)*127 + pos] = kv.z;
    kvbuf2[(4*q4 + 3)*127 + pos] = kv.w;
  }
  __syncthreads();

  // two positions (li, li+4) per iteration; independent chains for ILP
  for (int li = w; li < 27; li += 8) {
    const int liB0 = li + 4;
    const bool hasB = liB0 < 27;          // wave-uniform
    const int liB = hasB ? liB0 : li;

    const int lhA = li / 9,  lrA = li - lhA*9;
    const int ldA = lrA / 3, lwA = lrA - ldA*3;
    const int pA  = bN + (h0+lhA)*576 + (d0+ldA)*24 + (w0+lwA);
    const int hbA = c*127 + lhA*25 + ldA*5 + lwA;   // channel-major halo base
    const int lhB = liB / 9,  lrB = liB - lhB*9;
    const int ldB = lrB / 3,  lwB = lrB - ldB*3;
    const int pB  = bN + (h0+lhB)*576 + (d0+ldB)*24 + (w0+lwB);
    const int hbB = c*127 + lhB*25 + ldB*5 + lwB;

    const float qA = (float)Qh[(size_t)pA*64 + c];  // pre-scaled
    const float qB = (float)Qh[(size_t)pB*64 + c];

    float sA0 = 0.f, sA1 = 0.f, oA0 = 0.f, oA1 = 0.f;
    float sB0 = 0.f, sB1 = 0.f, oB0 = 0.f, oB1 = 0.f;
    #pragma unroll
    for (int m = 0; m < 5; ++m) {
      const float pfA = __builtin_amdgcn_exp2f(qA * mk[m]);
      const float pfB = __builtin_amdgcn_exp2f(qB * mk[m]);
      if (m & 1) { sA1 += pfA; oA1 = fmaf(pfA, mv[m], oA1);
                   sB1 += pfB; oB1 = fmaf(pfB, mv[m], oB1); }
      else       { sA0 += pfA; oA0 = fmaf(pfA, mv[m], oA0);
                   sB0 += pfB; oB0 = fmaf(pfB, mv[m], oB0); }
    }
    const unsigned int* kvA = &kvbuf2[hbA];
    const unsigned int* kvB = &kvbuf2[hbB];
    #pragma unroll
    for (int i = 0; i < 3; ++i)
      #pragma unroll
      for (int j = 0; j < 3; ++j)
        #pragma unroll
        for (int l2 = 0; l2 < 3; ++l2) {
          const int s4  = i*9 + j*3 + l2;
          const int off = i*25 + j*5 + l2;      // 0..62, ds_read2-fusable
          const unsigned a = kvA[off], bb2 = kvB[off];
          const float kA = __uint_as_float(a & 0xFFFF0000u);
          const float vA = __uint_as_float(a << 16);
          const float kB = __uint_as_float(bb2 & 0xFFFF0000u);
          const float vB = __uint_as_float(bb2 << 16);
          const float pfA = __builtin_amdgcn_exp2f(qA * kA);
          const float pfB = __builtin_amdgcn_exp2f(qB * kB);
          if (s4 & 1) { sA1 += pfA; oA1 = fmaf(pfA, vA, oA1);
                        sB1 += pfB; oB1 = fmaf(pfB, vB, oB1); }
          else        { sA0 += pfA; oA0 = fmaf(pfA, vA, oA0);
                        sB0 += pfB; oB0 = fmaf(pfB, vB, oB0); }
        }
    const float attA = (oA0 + oA1) * __builtin_amdgcn_rcpf(sA0 + sA1);
    const float attB = (oB0 + oB1) * __builtin_amdgcn_rcpf(sB0 + sB1);
    ATTh[(size_t)pA*64 + c] = (f16)attA;
    if (hasB) ATTh[(size_t)pB*64 + c] = (f16)attB;
  }
}

// ---------------------------------------------------------------------------
// Kernel 3: gate MFMA + blend + transpose + pool + last-block GRU.
// Per 64-pos tile: logit = G1 + Wg2*att (f16 MFMA, k1's verified fragment
// pattern); out = sigmoid(logit)*att + (1-sig)*x, written coalesced (C,N).
// Pool via per-block reduce + device atomics; counter-elected last block
// runs the GRU (reads pool through atomics).
// ---------------------------------------------------------------------------
__global__ __launch_bounds__(256) void outgate_kernel(
    const f16* __restrict__ ATTh, const f16* __restrict__ G1h,
    const float* __restrict__ x, const float* __restrict__ Wg,
    float* __restrict__ out,
    float* __restrict__ pool, const float* __restrict__ prev,
    const float* __restrict__ W_ih, const float* __restrict__ W_hh,
    const float* __restrict__ b_ih, const float* __restrict__ b_hh,
    float* __restrict__ outmem)
{
  __shared__ __align__(16) unsigned short wgs[64*64];   // f16 Wg2, swizzled
  __shared__ __align__(16) f16 att_s[64*64];            // [p][c], swizzled
  __shared__ __align__(16) f16 g1_s[64*64];             // [p][c], linear
  __shared__ __align__(16) float xf_s[64*65];           // [p*65+c] f32
  __shared__ __align__(16) float red[256];
  __shared__ float mu[128];
  __shared__ float gi[384];
  __shared__ float gh[384];
  __shared__ unsigned int lastf;
  const int t  = threadIdx.x;
  const int bi = blockIdx.x;
  const int b  = bi / 216;
  const int n0 = (bi - b*216) * 64;
  unsigned int* counter = (unsigned int*)(pool + 128);

  // ---- stage Wg2 (f16, row-XOR swizzle) ----
  #pragma unroll
  for (int k = 0; k < 4; ++k) {
    const int u  = t + k*256;
    const int r  = u >> 4;
    const int i0 = (u & 15) * 4;
    const float4 g4 = *(const float4*)&Wg[r*128 + 64 + i0];
    const int idx = (r*64 + i0) ^ ((r & 7) << 3);
    *(uint2*)&wgs[idx] = make_uint2(pkh2(g4.x, g4.y), pkh2(g4.z, g4.w));
  }
  // ---- stage att (swizzled) + g1 (linear): contiguous 2048-uint tiles ----
  {
    const unsigned int* attu = (const unsigned int*)(ATTh + (size_t)(b*NPOS + n0)*64);
    const unsigned int* g1u  = (const unsigned int*)(G1h  + (size_t)(b*NPOS + n0)*64);
    #pragma unroll
    for (int k = 0; k < 8; ++k) {
      const int u = t + k*256;           // uint index 0..2047
      const int p = u >> 5, c2 = u & 31; // f16 ch = 2*c2
      ((unsigned int*)att_s)[(p*32 + c2) ^ ((p & 7) << 2)] = attu[u];
      ((unsigned int*)g1_s)[u] = g1u[u];
    }
  }
  // ---- stage x tile (C,N)->[p*65+c] ----
  #pragma unroll
  for (int k = 0; k < 16; ++k) {
    const int u = t + k*256;
    const int cc = u >> 6, pp = u & 63;
    xf_s[pp*65 + cc] = x[(size_t)(b*64 + cc)*NPOS + n0 + pp];
  }
  __syncthreads();

  // ---- MFMA: logit_mm[c][p] = sum_j Wg2[c][j] * att[p][j] ----
  const int l   = t & 63;
  const int w   = t >> 6;
  const int lr  = l & 15;
  const int lkb = (l >> 4) * 8;
  const int swz = (lr & 7) << 3;
  f16x8 Aw[2];
  #pragma unroll
  for (int kk = 0; kk < 2; ++kk) {
    const int row = w*16 + lr;
    Aw[kk] = *(const f16x8*)&wgs[(row*64 + kk*32 + lkb) ^ swz];
  }
  f32x4 acc[4];
  #pragma unroll
  for (int nf = 0; nf < 4; ++nf) {
    f16x8 B0 = *(const f16x8*)&att_s[(((nf*16 + lr)*64) + 0*32 + lkb) ^ swz];
    f16x8 B1 = *(const f16x8*)&att_s[(((nf*16 + lr)*64) + 1*32 + lkb) ^ swz];
    f32x4 z = {0.f, 0.f, 0.f, 0.f};
    z = __builtin_amdgcn_mfma_f32_16x16x32_f16(Aw[0], B0, z, 0, 0, 0);
    acc[nf] = __builtin_amdgcn_mfma_f32_16x16x32_f16(Aw[1], B1, z, 0, 0, 0);
  }

  // ---- epilogue: ch = w*16+(l>>4)*4+e, pos = nf*16+lr ----
  const int c0 = w*16 + (l >> 4)*4;
  #pragma unroll
  for (int nf = 0; nf < 4; ++nf) {
    const int pl  = nf*16 + lr;
    const f16x4 av = *(const f16x4*)&att_s[(pl*64 + c0) ^ ((pl & 7) << 3)];
    const f16x4 gv = *(const f16x4*)&g1_s[pl*64 + c0];
    #pragma unroll
    for (int e = 0; e < 4; ++e) {
      const float attv  = (float)av[e];
      const float logit = acc[nf][e] + (float)gv[e];
      const float gate  = __builtin_amdgcn_rcpf(1.0f + __builtin_amdgcn_exp2f(-LOG2E * logit));
      const float xv    = xf_s[pl*65 + c0 + e];
      xf_s[pl*65 + c0 + e] = fmaf(gate, attv - xv, xv);   // owner-exclusive slot
    }
  }
  __syncthreads();

  // ---- coalesced (C,N) write-out ----
  #pragma unroll
  for (int i = 0; i < 16; ++i) {
    const int u = i*256 + t;
    const int cc = u >> 6, j = u & 63;
    out[(size_t)(b*64 + cc)*NPOS + n0 + j] = xf_s[j*65 + cc];
  }
  // ---- pool partial: sum over tile positions per channel ----
  {
    const int q = t >> 6, cc = t & 63;
    float s = 0.f;
    #pragma unroll
    for (int p2 = 0; p2 < 16; ++p2) s += xf_s[(q*16 + p2)*65 + cc];
    red[t] = s;
  }
  __syncthreads();
  if (t < 64) {
    const float s = red[t] + red[64 + t] + red[128 + t] + red[192 + t];
    atomicAdd(&pool[b*64 + t], s);
  }
  __syncthreads();                       // drain pool atomics (barrier waits vmcnt)
  if (t == 0) {
    __threadfence();
    lastf = (atomicAdd(counter, 1u) == (unsigned)(BTCH*216 - 1)) ? 1u : 0u;
  }
  __syncthreads();
  if (!lastf) return;

  // ---- GRU cell (elected last block) ----
  if (t < 128) mu[t] = atomicAdd(&pool[t], 0.0f) * (1.0f / (float)NPOS);
  __syncthreads();
  for (int r = t; r < 384; r += 256) {
    const int b2 = r / 192, j = r - b2*192;
    const float4* wi4 = (const float4*)(W_ih + (size_t)j*64);
    const float4* wh4 = (const float4*)(W_hh + (size_t)j*64);
    const float4* mu4 = (const float4*)(mu + b2*64);
    const float4* pv4 = (const float4*)(prev + b2*64);
    float sgi = b_ih[j], sgh = b_hh[j];
    #pragma unroll
    for (int k = 0; k < 16; ++k) {
      float4 wv = wi4[k], m4 = mu4[k];
      sgi = fmaf(wv.x, m4.x, sgi); sgi = fmaf(wv.y, m4.y, sgi);
      sgi = fmaf(wv.z, m4.z, sgi); sgi = fmaf(wv.w, m4.w, sgi);
      float4 hv = wh4[k], p4 = pv4[k];
      sgh = fmaf(hv.x, p4.x, sgh); sgh = fmaf(hv.y, p4.y, sgh);
      sgh = fmaf(hv.z, p4.z, sgh); sgh = fmaf(hv.w, p4.w, sgh);
    }
    gi[r] = sgi; gh[r] = sgh;
  }
  __syncthreads();
  if (t < 128) {
    const int b2 = t >> 6, cc = t & 63;
    float ir = gi[b2*192 + cc],       hr = gh[b2*192 + cc];
    float iz = gi[b2*192 + 64 + cc],  hz = gh[b2*192 + 64 + cc];
    float ii = gi[b2*192 + 128 + cc], hn = gh[b2*192 + 128 + cc];
    float rr = 1.0f / (1.0f + __builtin_amdgcn_exp2f(-LOG2E * (ir + hr)));
    float zz = 1.0f / (1.0f + __builtin_amdgcn_exp2f(-LOG2E * (iz + hz)));
    float ng = tanhf(ii + rr * hn);
    outmem[t] = (1.0f - zz) * ng + zz * prev[t];
  }
}

// ---------------------------------------------------------------------------
extern "C" void kernel_launch(void* const* d_in, const int* in_sizes, int n_in,
                              void* d_out, int out_size, void* d_ws, size_t ws_size,
                              hipStream_t stream) {
  const float* x    = (const float*)d_in[0];
  const float* prev = (const float*)d_in[1];
  const float* Wq   = (const float*)d_in[2];
  const float* bq   = (const float*)d_in[3];
  const float* Wk   = (const float*)d_in[4];
  const float* bk   = (const float*)d_in[5];
  const float* Wv   = (const float*)d_in[6];
  const float* bv   = (const float*)d_in[7];
  const float* memk = (const float*)d_in[8];
  const float* memv = (const float*)d_in[9];
  const float* Wg   = (const float*)d_in[10];
  const float* bg   = (const float*)d_in[11];
  const float* W_ih = (const float*)d_in[12];
  const float* W_hh = (const float*)d_in[13];
  const float* b_ih = (const float*)d_in[14];
  const float* b_hh = (const float*)d_in[15];

  float* out    = (float*)d_out;                 // (B,C,H,D,W)
  float* outmem = out + (size_t)BTCH*CDIM*NPOS;  // (B,C)

  const size_t SZ = (size_t)BTCH*NPOS*CDIM;      // 1769472
  float* wsf        = (float*)d_ws;
  f16*  Qh          = (f16*)wsf;                          // SZ f16
  unsigned int* KVp = (unsigned int*)(wsf + SZ/2);        // SZ u32
  f16*  G1h         = (f16*)(wsf + SZ/2 + SZ);            // SZ f16
  f16*  ATTh        = (f16*)(wsf + 2*SZ);                 // SZ f16
  float* pool       = wsf + 2*SZ + SZ/2;                  // 128 + counter

  qkvg_kernel<<<BTCH*216, 256, 0, stream>>>(x, Wq, bq, Wk, bk, Wv, bv, Wg, bg,
                                            Qh, KVp, G1h, pool);
  attn_kernel<<<BTCH*512, 256, 0, stream>>>(Qh, KVp, ATTh,
                                            bk, bv, memk, memv);
  outgate_kernel<<<BTCH*216, 256, 0, stream>>>(ATTh, G1h, x, Wg, out, pool, prev,
                                               W_ih, W_hh, b_ih, b_hh, outmem);
}